// Round 16
// baseline (188.391 us; speedup 1.0000x reference)
//
#include <hip/hip_runtime.h>

typedef __bf16 bf16;
typedef __bf16 bf16x8 __attribute__((ext_vector_type(8)));
typedef __bf16 bf16x4 __attribute__((ext_vector_type(4)));
typedef float floatx4 __attribute__((ext_vector_type(4)));

#define HIDDEN 1024
#define SEQ 2048
#define BATCH 4
#define ATT_SCALE 0.0625f
#define LN_EPS 1e-5f
#define WW (HIDDEN * HIDDEN)

__device__ __forceinline__ void gload_lds16(const void* g, void* l) {
    __builtin_amdgcn_global_load_lds(
        (const __attribute__((address_space(1))) unsigned int*)g,
        (__attribute__((address_space(3))) unsigned int*)l, 16, 0, 0);
}

#define GBAR() asm volatile("s_barrier" ::: "memory")
#define LGKM0() asm volatile("s_waitcnt lgkmcnt(0)" ::: "memory")
#define VMC(N) asm volatile("s_waitcnt vmcnt(" #N ")" ::: "memory")
#define MFMA(a, b, c) __builtin_amdgcn_mfma_f32_16x16x32_bf16(a, b, c, 0, 0, 0)
#define MFMA8(a, b, c) __builtin_amdgcn_mfma_f32_16x16x32_fp8_fp8(a, b, c, 0, 0, 0)

// fp8 e4m3 conversions via hardware cvt_pk (saturating)
__device__ __forceinline__ unsigned char to_fp8(float f) {
    return (unsigned char)(__builtin_amdgcn_cvt_pk_fp8_f32(f, 0.0f, 0, 0) & 0xff);
}
__device__ __forceinline__ unsigned int to_fp8x2(float a, float b) {
    return __builtin_amdgcn_cvt_pk_fp8_f32(a, b, 0, 0) & 0xffff;
}

// ---------------- fp32 -> fp8 conversion (8 elems/thread) ----------------
__global__ void cvt_f32_fp8(const float* __restrict__ in, unsigned char* __restrict__ out, int n8) {
    int i = blockIdx.x * blockDim.x + threadIdx.x;
    if (i >= n8) return;
    float4 v0 = ((const float4*)in)[i * 2];
    float4 v1 = ((const float4*)in)[i * 2 + 1];
    unsigned int lo = to_fp8x2(v0.x, v0.y) | (to_fp8x2(v0.z, v0.w) << 16);
    unsigned int hi = to_fp8x2(v1.x, v1.y) | (to_fp8x2(v1.z, v1.w) << 16);
    ((uint2*)out)[i] = make_uint2(lo, hi);
}

// ---------------- weight prep: z=0..2 transpose fp32->bf16 ; z=3 plain convert Wo ----------
__global__ void transpose_w4(const float* __restrict__ s0, const float* __restrict__ s1,
                             const float* __restrict__ s2, const float* __restrict__ s3,
                             bf16* __restrict__ d0p, bf16* __restrict__ d1p,
                             bf16* __restrict__ d2p, bf16* __restrict__ d3p) {
    const int zz = blockIdx.z;
    const float* in = (zz == 0) ? s0 : (zz == 1) ? s1 : (zz == 2) ? s2 : s3;
    bf16* out = (zz == 0) ? d0p : (zz == 1) ? d1p : (zz == 2) ? d2p : d3p;
    const int d0 = blockIdx.x * 64;
    const int f0 = blockIdx.y * 64;
    const int t = threadIdx.x;
    const int r = t >> 4;
    const int c = (t & 15) * 4;
    if (zz == 3) {
#pragma unroll
        for (int i = 0; i < 4; ++i) {
            float4 v = *(const float4*)&in[(long)(f0 + r + i * 16) * HIDDEN + d0 + c];
            bf16x4 b;
            b[0] = (bf16)v.x; b[1] = (bf16)v.y; b[2] = (bf16)v.z; b[3] = (bf16)v.w;
            *(bf16x4*)&out[(long)(f0 + r + i * 16) * HIDDEN + d0 + c] = b;
        }
        return;
    }
    __shared__ __attribute__((aligned(16))) bf16 tile[64][72];
#pragma unroll
    for (int i = 0; i < 4; ++i) {
        float4 v = *(const float4*)&in[(long)(f0 + r + i * 16) * HIDDEN + d0 + c];
        bf16x4 b;
        b[0] = (bf16)v.x; b[1] = (bf16)v.y; b[2] = (bf16)v.z; b[3] = (bf16)v.w;
        *(bf16x4*)&tile[r + i * 16][c] = b;
    }
    __syncthreads();
#pragma unroll
    for (int i = 0; i < 4; ++i) {
        const int dr = r + i * 16;
        bf16x4 o;
#pragma unroll
        for (int j = 0; j < 4; ++j) o[j] = tile[c + j][dr];
        *(bf16x4*)&out[(long)(d0 + dr) * HIDDEN + f0 + c] = o;
    }
}

// ---------------- bf16 8-phase GEMM (weight prep only): C = A*B^T, z = ks*zmod + mat
// MODE 0: bf16 C = acc*scale (used for split-K bf16 partials with scale=1)
template <int MODE>
__global__ __launch_bounds__(512, 2)
void gemm8p(const bf16* A, const bf16* Bw, void* __restrict__ Cout,
            int lda, int ldb, int ldc, int K, float scale,
            long sA, long sB, long sC, int zmod) {
    __shared__ __attribute__((aligned(16))) char lds[131072];

    const int gx = gridDim.x;
    const int nblk = gx * gridDim.y;
    const int bid = blockIdx.y * gx + blockIdx.x;
    const int cpx = nblk >> 3;
    const int sbid = (nblk & 7) ? bid : (bid & 7) * cpx + (bid >> 3);
    const int bx = sbid % gx, by = sbid / gx;

    const int z = blockIdx.z;
    const int mat = z % zmod, ks = z / zmod;
    const char* Ab = (const char*)(A + (long)mat * sA + (long)ks * K);
    const char* Bb = (const char*)(Bw + (long)mat * sB + (long)ks * K);
    const long lda2 = lda * 2L, ldb2 = ldb * 2L;

    const int t = threadIdx.x;
    const int lane = t & 63;
    const int w = t >> 6;
    const int wm = w >> 2;
    const int wn = w & 3;
    const int l15 = lane & 15;
    const int l4 = lane >> 4;

    const int row0 = by * 256;
    const int col0 = bx * 256;

    const int sc = ((((t & 3) - ((t >> 3) & 3)) & 3) << 4);
    const char* aS[2];
    const char* bS[2];
#pragma unroll
    for (int uu = 0; uu < 2; ++uu) {
        aS[uu] = Ab + (long)(row0 + uu * 128 + (t >> 2)) * lda2 + sc;
        bS[uu] = Bb + (long)(col0 + uu * 128 + (t >> 2)) * ldb2 + sc;
    }

    auto STAGE = [&](char* dstu, const char* const* sp, long koff) {
        gload_lds16(sp[0] + koff, dstu + t * 16);
        gload_lds16(sp[1] + koff, dstu + 8192 + t * 16);
    };

    floatx4 acc[8][4] = {};
    const int nk = K / 64;

    STAGE(lds + 0,     aS, 0);
    STAGE(lds + 16384, bS, 0);
    STAGE(lds + 32768, aS, 64);
    STAGE(lds + 49152, bS, 64);
    VMC(4);
    GBAR();

    for (int tt = 0; tt < nk; ++tt) {
        const char* cb = lds + (tt & 1) * 65536;
        char* nb = lds + ((tt & 1) ^ 1) * 65536;
        const long nko = (long)((tt + 1 < nk) ? tt + 1 : nk - 1) * 128;

        auto RDA = [&](int kk, int m) {
            int lr = wm * 128 + m * 16 + l15;
            return *(const bf16x8*)(cb + kk * 32768 + lr * 64 + ((((lr >> 1) + l4) & 3) << 4));
        };
        auto RDB = [&](int kk, int n) {
            int lr = wn * 64 + n * 16 + l15;
            return *(const bf16x8*)(cb + 16384 + kk * 32768 + lr * 64 + ((((lr >> 1) + l4) & 3) << 4));
        };

        bf16x8 a[4], b0[4], b1[4];

#pragma unroll
        for (int m = 0; m < 4; ++m) a[m] = RDA(0, m);
#pragma unroll
        for (int n = 0; n < 4; ++n) b0[n] = RDB(0, n);
        STAGE(nb + 0, aS, nko);
        GBAR();
        LGKM0();
        __builtin_amdgcn_s_setprio(1);
#pragma unroll
        for (int m = 0; m < 4; ++m)
#pragma unroll
            for (int n = 0; n < 4; ++n) acc[m][n] = MFMA(a[m], b0[n], acc[m][n]);
        __builtin_amdgcn_s_setprio(0);
        GBAR();

#pragma unroll
        for (int m = 0; m < 4; ++m) a[m] = RDA(0, 4 + m);
        STAGE(nb + 16384, bS, nko);
        GBAR();
        LGKM0();
        __builtin_amdgcn_s_setprio(1);
#pragma unroll
        for (int m = 0; m < 4; ++m)
#pragma unroll
            for (int n = 0; n < 4; ++n) acc[4 + m][n] = MFMA(a[m], b0[n], acc[4 + m][n]);
        __builtin_amdgcn_s_setprio(0);
        VMC(4);
        GBAR();

#pragma unroll
        for (int m = 0; m < 4; ++m) a[m] = RDA(1, m);
#pragma unroll
        for (int n = 0; n < 4; ++n) b1[n] = RDB(1, n);
        STAGE(nb + 32768, aS, nko + 64);
        GBAR();
        LGKM0();
        __builtin_amdgcn_s_setprio(1);
#pragma unroll
        for (int m = 0; m < 4; ++m)
#pragma unroll
            for (int n = 0; n < 4; ++n) acc[m][n] = MFMA(a[m], b1[n], acc[m][n]);
        __builtin_amdgcn_s_setprio(0);
        GBAR();

#pragma unroll
        for (int m = 0; m < 4; ++m) a[m] = RDA(1, 4 + m);
        STAGE(nb + 49152, bS, nko + 64);
        GBAR();
        LGKM0();
        __builtin_amdgcn_s_setprio(1);
#pragma unroll
        for (int m = 0; m < 4; ++m)
#pragma unroll
            for (int n = 0; n < 4; ++n) acc[4 + m][n] = MFMA(a[m], b1[n], acc[4 + m][n]);
        __builtin_amdgcn_s_setprio(0);
        VMC(4);
        GBAR();
    }
    VMC(0);

    const int rq = l4 * 4;
    bf16* C = ((bf16*)Cout) + (long)z * sC;
#pragma unroll
    for (int m = 0; m < 8; ++m)
#pragma unroll
        for (int i = 0; i < 4; ++i) {
            long gr = row0 + wm * 128 + m * 16 + rq + i;
#pragma unroll
            for (int n = 0; n < 4; ++n) {
                int gc = col0 + wn * 64 + n * 16 + l15;
                C[gr * ldc + gc] = (bf16)(acc[m][n][i] * scale);
            }
        }
}

// ---------------- fp8 GEMM, 4-wave: C = A (MxK_sub) * B^T, fp8 e4m3, z = ks*zmod + mat
// 256 thr = 4 waves (2M x 2N), BM=256, BN=128, wave tile 128x64, K-64 slots.
// LDS 48KB: 2 slots x {A-k0 8K, A-k1 8K, B-k0 4K, B-k1 4K}; A unit = 256 rows x 32B,
// B unit = 128 rows x 32B. 16B-half rotation u' = (u + (r>>2)) & 1 (<=2-way = free);
// gload_lds dest linear, source inverse-rotated. Per slot: STAGE s+1 first (6 gloads),
// 24 b64 frag reads + 64 MFMA (compiler-interleaved), vmcnt(0)+barrier. 48KB LDS ->
// up to 3 blocks/CU; grids >= 512 so >=2 co-resident blocks hide each other's drain.
// MODE 0: bf16 C = acc*scale ; MODE 1: fp8 C = acc*scale
template <int MODE>
__global__ __launch_bounds__(256, 3)
void gemmf8(const unsigned char* A, const unsigned char* Bw, void* __restrict__ Cout,
            int lda, int ldb, int ldc, int K, float scale,
            long sA, long sB, long sC, int zmod) {
    __shared__ __attribute__((aligned(16))) char lds[49152];

    const int gx = gridDim.x;
    const int nblk = gx * gridDim.y;
    const int bid = blockIdx.y * gx + blockIdx.x;
    const int cpx = nblk >> 3;
    const int sbid = (nblk & 7) ? bid : (bid & 7) * cpx + (bid >> 3);
    const int bx = sbid % gx, by = sbid / gx;

    const int z = blockIdx.z;
    const int mat = z % zmod, ks = z / zmod;
    const unsigned char* Ab = A + (long)mat * sA + (long)ks * K;
    const unsigned char* Bb = Bw + (long)mat * sB + (long)ks * K;

    const int t = threadIdx.x;
    const int lane = t & 63;
    const int w = t >> 6;
    const int wm = w >> 1;      // 0..1
    const int wn = w & 1;       // 0..1
    const int l15 = lane & 15;
    const int l4 = lane >> 4;

    const int row0 = by * 256;
    const int col0 = bx * 128;

    // staging: thread t covers 16B: row r = t>>1 (+128*uu for A), stored-half t&1,
    // global-half u = ((t&1) + (r>>2)) & 1 = ((t&1) + (t>>3)) & 1
    const int r_st = t >> 1;
    const int u_g = ((t & 1) + (t >> 3)) & 1;
    const unsigned char* aS0 = Ab + (long)(row0 + r_st) * lda + u_g * 16;
    const unsigned char* aS1 = Ab + (long)(row0 + 128 + r_st) * lda + u_g * 16;
    const unsigned char* bS0 = Bb + (long)(col0 + r_st) * ldb + u_g * 16;
    const int ld16 = t * 16;

    auto STAGE = [&](int slot, long koff) {
        char* base = lds + slot * 24576;
        gload_lds16(aS0 + koff,      base + ld16);             // A-k0 rows 0..127
        gload_lds16(aS1 + koff,      base + 4096 + ld16);      // A-k0 rows 128..255
        gload_lds16(aS0 + koff + 32, base + 8192 + ld16);      // A-k1 rows 0..127
        gload_lds16(aS1 + koff + 32, base + 12288 + ld16);     // A-k1 rows 128..255
        gload_lds16(bS0 + koff,      base + 16384 + ld16);     // B-k0
        gload_lds16(bS0 + koff + 32, base + 20480 + ld16);     // B-k1
    };

    floatx4 acc[8][4] = {};
    const int nk = K / 64;

    STAGE(0, 0);
    VMC(0);
    GBAR();

    for (int s = 0; s < nk; ++s) {
        const char* sb = lds + (s & 1) * 24576;
        const long pko = (long)((s + 1 < nk) ? s + 1 : nk - 1) * 64;
        STAGE((s + 1) & 1, pko);

        auto RD = [&](const char* unit, int r) {
            int addr = r * 32 + ((((l4 >> 1) + (r >> 2)) & 1) << 4) + ((l4 & 1) << 3);
            return *(const long*)(unit + addr);
        };

        long a[8], b[4];
        // kk = 0 (A unit at 0, 256 rows; B unit at 16384, 128 rows)
#pragma unroll
        for (int n = 0; n < 4; ++n) b[n] = RD(sb + 16384, wn * 64 + n * 16 + l15);
#pragma unroll
        for (int m = 0; m < 8; ++m) a[m] = RD(sb, wm * 128 + m * 16 + l15);
        __builtin_amdgcn_s_setprio(1);
#pragma unroll
        for (int m = 0; m < 8; ++m)
#pragma unroll
            for (int n = 0; n < 4; ++n) acc[m][n] = MFMA8(a[m], b[n], acc[m][n]);
        __builtin_amdgcn_s_setprio(0);
        // kk = 1 (A unit at 8192, B unit at 20480)
#pragma unroll
        for (int n = 0; n < 4; ++n) b[n] = RD(sb + 20480, wn * 64 + n * 16 + l15);
#pragma unroll
        for (int m = 0; m < 8; ++m) a[m] = RD(sb + 8192, wm * 128 + m * 16 + l15);
        __builtin_amdgcn_s_setprio(1);
#pragma unroll
        for (int m = 0; m < 8; ++m)
#pragma unroll
            for (int n = 0; n < 4; ++n) acc[m][n] = MFMA8(a[m], b[n], acc[m][n]);
        __builtin_amdgcn_s_setprio(0);

        VMC(0);
        GBAR();
    }

    const int rq = l4 * 4;
    if constexpr (MODE == 0) {
        bf16* C = ((bf16*)Cout) + (long)z * sC;
#pragma unroll
        for (int m = 0; m < 8; ++m)
#pragma unroll
            for (int i = 0; i < 4; ++i) {
                long gr = row0 + wm * 128 + m * 16 + rq + i;
#pragma unroll
                for (int n = 0; n < 4; ++n) {
                    int gc = col0 + wn * 64 + n * 16 + l15;
                    C[gr * ldc + gc] = (bf16)(acc[m][n][i] * scale);
                }
            }
    } else {
        unsigned char* C = ((unsigned char*)Cout) + (long)z * sC;
#pragma unroll
        for (int m = 0; m < 8; ++m)
#pragma unroll
            for (int i = 0; i < 4; ++i) {
                long gr = row0 + wm * 128 + m * 16 + rq + i;
#pragma unroll
                for (int n = 0; n < 4; ++n) {
                    int gc = col0 + wn * 64 + n * 16 + l15;
                    C[gr * ldc + gc] = to_fp8(acc[m][n][i] * scale);
                }
            }
    }
}

// ---------------- reduce Gt/Wc bf16 partials (planes z=ks*2+mat, ks 0..3) -> wgc fp8 (x64) ----
__global__ void reduce_wgc(const bf16* __restrict__ p, unsigned char* __restrict__ out) {
    int i = blockIdx.x * blockDim.x + threadIdx.x;
    int e = i * 4;
    int mat = e >> 20;
    int local = e & (WW - 1);
    float s0 = 0, s1 = 0, s2 = 0, s3 = 0;
#pragma unroll
    for (int ksp = 0; ksp < 4; ++ksp) {
        bf16x4 a = *(const bf16x4*)(p + (long)(ksp * 2 + mat) * WW + local);
        s0 += (float)a[0]; s1 += (float)a[1]; s2 += (float)a[2]; s3 += (float)a[3];
    }
    unsigned int pk = to_fp8x2(s0 * 64.f, s1 * 64.f) | (to_fp8x2(s2 * 64.f, s3 * 64.f) << 16);
    *(unsigned int*)&out[e] = pk;
}

// ---------------- row softmax: bf16 scores -> fp8 probs x256 ----------------
__global__ void softmax_rows(const bf16* __restrict__ S, unsigned char* __restrict__ P,
                             const int* __restrict__ mask) {
    const int b = blockIdx.y;
    const int row = blockIdx.x;
    const bf16* srow = S + ((long)b * SEQ + row) * SEQ;
    unsigned char* prow = P + ((long)b * SEQ + row) * SEQ;
    const int* mrow = mask + b * SEQ;
    const int t = threadIdx.x;

    bf16x8 sv = *(const bf16x8*)&srow[t * 8];
    int4 m0 = ((const int4*)mrow)[t * 2];
    int4 m1 = ((const int4*)mrow)[t * 2 + 1];
    int mk[8] = {m0.x, m0.y, m0.z, m0.w, m1.x, m1.y, m1.z, m1.w};

    float v[8];
    float mx = -1e30f;
#pragma unroll
    for (int j = 0; j < 8; ++j) {
        float s = (float)sv[j];
        if (mk[j] == 0) s = -1e9f;
        v[j] = s;
        mx = fmaxf(mx, s);
    }
    __shared__ float redm[4], reds[4];
#pragma unroll
    for (int off = 32; off > 0; off >>= 1) mx = fmaxf(mx, __shfl_down(mx, off));
    if ((t & 63) == 0) redm[t >> 6] = mx;
    __syncthreads();
    mx = fmaxf(fmaxf(redm[0], redm[1]), fmaxf(redm[2], redm[3]));

    float sum = 0.f;
#pragma unroll
    for (int j = 0; j < 8; ++j) {
        v[j] = __expf(v[j] - mx);
        sum += v[j];
    }
#pragma unroll
    for (int off = 32; off > 0; off >>= 1) sum += __shfl_down(sum, off);
    if ((t & 63) == 0) reds[t >> 6] = sum;
    __syncthreads();
    sum = reds[0] + reds[1] + reds[2] + reds[3];
    float inv = 256.0f / sum;

    unsigned int lo = to_fp8x2(v[0] * inv, v[1] * inv) | (to_fp8x2(v[2] * inv, v[3] * inv) << 16);
    unsigned int hi = to_fp8x2(v[4] * inv, v[5] * inv) | (to_fp8x2(v[6] * inv, v[7] * inv) << 16);
    *(uint2*)&prow[t * 8] = make_uint2(lo, hi);
}

// ---------------- transpose VWc fp8 (yv cols 1024..2047) -> vt (1024 x SEQ per batch) ----
__global__ void transpose_v8(const unsigned char* __restrict__ yv, unsigned char* __restrict__ out) {
    __shared__ unsigned char tile[64][68];
    const int z = blockIdx.z;
    const unsigned char* ib = yv + (long)z * SEQ * 2048 + 1024;
    unsigned char* ob = out + (long)z * (long)HIDDEN * SEQ;
    const int d0 = blockIdx.x * 64;
    const int s0 = blockIdx.y * 64;
    const int t = threadIdx.x;
    const int r = t >> 4;
    const int c = (t & 15) * 4;
#pragma unroll
    for (int i = 0; i < 4; ++i) {
        uchar4 v = *(const uchar4*)&ib[(long)(s0 + r + i * 16) * 2048 + d0 + c];
        *(uchar4*)&tile[r + i * 16][c] = v;
    }
    __syncthreads();
#pragma unroll
    for (int i = 0; i < 4; ++i) {
        const int dr = r + i * 16;
        uchar4 o;
        o.x = tile[c + 0][dr]; o.y = tile[c + 1][dr];
        o.z = tile[c + 2][dr]; o.w = tile[c + 3][dr];
        *(uchar4*)&ob[(long)(d0 + dr) * SEQ + s0 + c] = o;
    }
}

// ---------------- LayerNorm fused with PV split-K reduce + bias + residual ----------------
__global__ void layernorm_out(const bf16* __restrict__ pp, const float* __restrict__ x,
                              const float* __restrict__ bo, const float* __restrict__ gamma,
                              const float* __restrict__ beta, float* __restrict__ out) {
    const long row = blockIdx.x;
    const int b = (int)(row >> 11);
    const int s = (int)(row & 2047);
    const bf16* r0 = pp + ((long)b * SEQ + s) * HIDDEN;
    const bf16* r1 = r0 + 4L * SEQ * HIDDEN;
    const int t = threadIdx.x;

    bf16x4 a0 = ((const bf16x4*)r0)[t];
    bf16x4 a1 = ((const bf16x4*)r1)[t];
    float4 xv = ((const float4*)(x + row * HIDDEN))[t];
    float4 bv = ((const float4*)bo)[t];
    float4 v;
    v.x = (float)a0[0] + (float)a1[0] + bv.x + xv.x;
    v.y = (float)a0[1] + (float)a1[1] + bv.y + xv.y;
    v.z = (float)a0[2] + (float)a1[2] + bv.z + xv.z;
    v.w = (float)a0[3] + (float)a1[3] + bv.w + xv.w;

    float ssum = v.x + v.y + v.z + v.w;
    float sq = v.x * v.x + v.y * v.y + v.z * v.z + v.w * v.w;
    __shared__ float rs[4], rq[4];
#pragma unroll
    for (int off = 32; off > 0; off >>= 1) {
        ssum += __shfl_down(ssum, off);
        sq += __shfl_down(sq, off);
    }
    if ((t & 63) == 0) { rs[t >> 6] = ssum; rq[t >> 6] = sq; }
    __syncthreads();
    ssum = rs[0] + rs[1] + rs[2] + rs[3];
    sq = rq[0] + rq[1] + rq[2] + rq[3];
    float mu = ssum * (1.0f / HIDDEN);
    float var = sq * (1.0f / HIDDEN) - mu * mu;
    float rinv = rsqrtf(var + LN_EPS);
    float4 g = ((const float4*)gamma)[t];
    float4 bt = ((const float4*)beta)[t];
    float4 o;
    o.x = (v.x - mu) * rinv * g.x + bt.x;
    o.y = (v.y - mu) * rinv * g.y + bt.y;
    o.z = (v.z - mu) * rinv * g.z + bt.z;
    o.w = (v.w - mu) * rinv * g.w + bt.w;
    ((float4*)(out + row * HIDDEN))[t] = o;
}

// ---------------- launch ----------------
extern "C" void kernel_launch(void* const* d_in, const int* in_sizes, int n_in,
                              void* d_out, int out_size, void* d_ws, size_t ws_size,
                              hipStream_t stream) {
    const float* x     = (const float*)d_in[0];
    const int*   mask  = (const int*)d_in[1];
    const float* Wq    = (const float*)d_in[2];
    const float* Wk    = (const float*)d_in[3];
    const float* Wv    = (const float*)d_in[4];
    const float* Wo    = (const float*)d_in[5];
    const float* bo    = (const float*)d_in[6];
    const float* gamma = (const float*)d_in[7];
    const float* beta  = (const float*)d_in[8];
    float* out = (float*)d_out;

    char* ws = (char*)d_ws;
    const long MB = 1024L * 1024L;
    unsigned char* xb8  = (unsigned char*)(ws + 0 * MB);   // 8 MB (8192x1024 fp8)
    unsigned char* yv8  = (unsigned char*)(ws + 8 * MB);   // 16 MB (8192x2048 fp8) [y | VWc]
    unsigned char* vt8  = (unsigned char*)(ws + 24 * MB);  // 8 MB (per batch 1024x2048 fp8)
    unsigned char* wgc8 = (unsigned char*)(ws + 32 * MB);  // 2 MB (2048x1024 fp8, x64)
    bf16* wkT = (bf16*)(ws + 34 * MB);                     // 2 MB
    bf16* wo  = (bf16*)(ws + 36 * MB);                     // 2 MB
    bf16* wqT = (bf16*)(ws + 38 * MB);                     // 2 MB
    bf16* wvT = (bf16*)(ws + 40 * MB);                     // 2 MB
    bf16* S   = (bf16*)(ws + 42 * MB);                     // 32 MB bf16 scores
    bf16* wgcp = (bf16*)(ws + 42 * MB);                    // 16 MB bf16 partials (dead before S)
    bf16* pp  = (bf16*)(ws + 42 * MB);                     // 32 MB PV partials (over S, after softmax)
    unsigned char* P8 = (unsigned char*)(ws + 74 * MB);    // 16 MB fp8 probs x256

    const int BS = BATCH * SEQ;  // 8192
    dim3 blk256(256), blk512(512);

    // input + weight prep
    cvt_f32_fp8<<<dim3(BS * HIDDEN / 8 / 256), blk256, 0, stream>>>(x, xb8, BS * HIDDEN / 8);
    transpose_w4<<<dim3(16, 16, 4), blk256, 0, stream>>>(Wq, Wk, Wv, Wo, wqT, wkT, wvT, wo);

    // Gt/Wc split-K=4 (bf16): z = ks*2 + mat, K_sub=256, bf16 partials. grid (4,4,8)
    gemm8p<0><<<dim3(1024 / 256, 1024 / 256, 8), blk512, 0, stream>>>(
        wkT, wqT, wgcp, HIDDEN, HIDDEN, HIDDEN, 256, 1.0f,
        (long)WW, (long)WW, (long)WW, 2);
    reduce_wgc<<<dim3(2 * WW / 4 / 256), blk256, 0, stream>>>(wgcp, wgc8);

    // fused projection (fp8): yv8 = xb8 * wgc8^T / 64. grid 16x32 = 512
    gemmf8<1><<<dim3(2048 / 128, BS / 256, 1), blk256, 0, stream>>>(
        xb8, wgc8, yv8, HIDDEN, HIDDEN, 2048, HIDDEN, 1.0f / 64.0f, 0, 0, 0, 1);

    // VWc -> vt per batch (fp8)
    transpose_v8<<<dim3(HIDDEN / 64, SEQ / 64, BATCH), blk256, 0, stream>>>(yv8, vt8);

    // scores (fp8 in, bf16 out): per batch y * x^T * SCALE. grid 16x8x4 = 512
    gemmf8<0><<<dim3(SEQ / 128, SEQ / 256, BATCH), blk256, 0, stream>>>(
        yv8, xb8, S, 2048, HIDDEN, SEQ, HIDDEN, ATT_SCALE,
        (long)SEQ * 2048, (long)SEQ * HIDDEN, (long)SEQ * SEQ, 4);

    // softmax -> fp8 probs x256
    softmax_rows<<<dim3(SEQ, BATCH), blk256, 0, stream>>>(S, P8, mask);

    // PV split-K=2 (fp8): z = ks*4 + b, K_sub=1024, bf16 partials x(1/256). grid (8,8,8) = 512
    gemmf8<0><<<dim3(HIDDEN / 128, SEQ / 256, 8), blk256, 0, stream>>>(
        P8, vt8, pp, SEQ, SEQ, HIDDEN, 1024, 1.0f / 256.0f,
        (long)SEQ * SEQ, (long)HIDDEN * SEQ, (long)SEQ * HIDDEN, 4);

    // LN fused with partial-reduce + bias + residual
    layernorm_out<<<dim3(BS), blk256, 0, stream>>>(pp, x, bo, gamma, beta, out);
}

// Round 17
// 164.311 us; speedup vs baseline: 1.1466x; 1.1466x over previous
//
#include <hip/hip_runtime.h>

typedef __bf16 bf16;
typedef __bf16 bf16x8 __attribute__((ext_vector_type(8)));
typedef __bf16 bf16x4 __attribute__((ext_vector_type(4)));
typedef float floatx4 __attribute__((ext_vector_type(4)));

#define HIDDEN 1024
#define SEQ 2048
#define BATCH 4
#define ATT_SCALE 0.0625f
#define LN_EPS 1e-5f
#define WW (HIDDEN * HIDDEN)

__device__ __forceinline__ void gload_lds16(const void* g, void* l) {
    __builtin_amdgcn_global_load_lds(
        (const __attribute__((address_space(1))) unsigned int*)g,
        (__attribute__((address_space(3))) unsigned int*)l, 16, 0, 0);
}

#define GBAR() asm volatile("s_barrier" ::: "memory")
#define LGKM0() asm volatile("s_waitcnt lgkmcnt(0)" ::: "memory")
#define VMC(N) asm volatile("s_waitcnt vmcnt(" #N ")" ::: "memory")
#define MFMA(a, b, c) __builtin_amdgcn_mfma_f32_16x16x32_bf16(a, b, c, 0, 0, 0)
#define MFMA8(a, b, c) __builtin_amdgcn_mfma_f32_16x16x32_fp8_fp8(a, b, c, 0, 0, 0)

// fp8 e4m3 conversions via hardware cvt_pk (saturating)
__device__ __forceinline__ unsigned char to_fp8(float f) {
    return (unsigned char)(__builtin_amdgcn_cvt_pk_fp8_f32(f, 0.0f, 0, 0) & 0xff);
}
__device__ __forceinline__ unsigned int to_fp8x2(float a, float b) {
    return __builtin_amdgcn_cvt_pk_fp8_f32(a, b, 0, 0) & 0xffff;
}

// ---------------- fp32 -> fp8 conversion (8 elems/thread) ----------------
__global__ void cvt_f32_fp8(const float* __restrict__ in, unsigned char* __restrict__ out, int n8) {
    int i = blockIdx.x * blockDim.x + threadIdx.x;
    if (i >= n8) return;
    float4 v0 = ((const float4*)in)[i * 2];
    float4 v1 = ((const float4*)in)[i * 2 + 1];
    unsigned int lo = to_fp8x2(v0.x, v0.y) | (to_fp8x2(v0.z, v0.w) << 16);
    unsigned int hi = to_fp8x2(v1.x, v1.y) | (to_fp8x2(v1.z, v1.w) << 16);
    ((uint2*)out)[i] = make_uint2(lo, hi);
}

// ---------------- weight prep: z=0..2 transpose fp32->bf16 ; z=3 plain convert Wo ----------
__global__ void transpose_w4(const float* __restrict__ s0, const float* __restrict__ s1,
                             const float* __restrict__ s2, const float* __restrict__ s3,
                             bf16* __restrict__ d0p, bf16* __restrict__ d1p,
                             bf16* __restrict__ d2p, bf16* __restrict__ d3p) {
    const int zz = blockIdx.z;
    const float* in = (zz == 0) ? s0 : (zz == 1) ? s1 : (zz == 2) ? s2 : s3;
    bf16* out = (zz == 0) ? d0p : (zz == 1) ? d1p : (zz == 2) ? d2p : d3p;
    const int d0 = blockIdx.x * 64;
    const int f0 = blockIdx.y * 64;
    const int t = threadIdx.x;
    const int r = t >> 4;
    const int c = (t & 15) * 4;
    if (zz == 3) {
#pragma unroll
        for (int i = 0; i < 4; ++i) {
            float4 v = *(const float4*)&in[(long)(f0 + r + i * 16) * HIDDEN + d0 + c];
            bf16x4 b;
            b[0] = (bf16)v.x; b[1] = (bf16)v.y; b[2] = (bf16)v.z; b[3] = (bf16)v.w;
            *(bf16x4*)&out[(long)(f0 + r + i * 16) * HIDDEN + d0 + c] = b;
        }
        return;
    }
    __shared__ __attribute__((aligned(16))) bf16 tile[64][72];
#pragma unroll
    for (int i = 0; i < 4; ++i) {
        float4 v = *(const float4*)&in[(long)(f0 + r + i * 16) * HIDDEN + d0 + c];
        bf16x4 b;
        b[0] = (bf16)v.x; b[1] = (bf16)v.y; b[2] = (bf16)v.z; b[3] = (bf16)v.w;
        *(bf16x4*)&tile[r + i * 16][c] = b;
    }
    __syncthreads();
#pragma unroll
    for (int i = 0; i < 4; ++i) {
        const int dr = r + i * 16;
        bf16x4 o;
#pragma unroll
        for (int j = 0; j < 4; ++j) o[j] = tile[c + j][dr];
        *(bf16x4*)&out[(long)(d0 + dr) * HIDDEN + f0 + c] = o;
    }
}

// ---------------- bf16 8-phase GEMM (weight prep only): C = A*B^T, z = ks*zmod + mat
// MODE 0: bf16 C = acc*scale (split-K bf16 partials with scale=1)
template <int MODE>
__global__ __launch_bounds__(512, 2)
void gemm8p(const bf16* A, const bf16* Bw, void* __restrict__ Cout,
            int lda, int ldb, int ldc, int K, float scale,
            long sA, long sB, long sC, int zmod) {
    __shared__ __attribute__((aligned(16))) char lds[131072];

    const int gx = gridDim.x;
    const int nblk = gx * gridDim.y;
    const int bid = blockIdx.y * gx + blockIdx.x;
    const int cpx = nblk >> 3;
    const int sbid = (nblk & 7) ? bid : (bid & 7) * cpx + (bid >> 3);
    const int bx = sbid % gx, by = sbid / gx;

    const int z = blockIdx.z;
    const int mat = z % zmod, ks = z / zmod;
    const char* Ab = (const char*)(A + (long)mat * sA + (long)ks * K);
    const char* Bb = (const char*)(Bw + (long)mat * sB + (long)ks * K);
    const long lda2 = lda * 2L, ldb2 = ldb * 2L;

    const int t = threadIdx.x;
    const int lane = t & 63;
    const int w = t >> 6;
    const int wm = w >> 2;
    const int wn = w & 3;
    const int l15 = lane & 15;
    const int l4 = lane >> 4;

    const int row0 = by * 256;
    const int col0 = bx * 256;

    const int sc = ((((t & 3) - ((t >> 3) & 3)) & 3) << 4);
    const char* aS[2];
    const char* bS[2];
#pragma unroll
    for (int uu = 0; uu < 2; ++uu) {
        aS[uu] = Ab + (long)(row0 + uu * 128 + (t >> 2)) * lda2 + sc;
        bS[uu] = Bb + (long)(col0 + uu * 128 + (t >> 2)) * ldb2 + sc;
    }

    auto STAGE = [&](char* dstu, const char* const* sp, long koff) {
        gload_lds16(sp[0] + koff, dstu + t * 16);
        gload_lds16(sp[1] + koff, dstu + 8192 + t * 16);
    };

    floatx4 acc[8][4] = {};
    const int nk = K / 64;

    STAGE(lds + 0,     aS, 0);
    STAGE(lds + 16384, bS, 0);
    STAGE(lds + 32768, aS, 64);
    STAGE(lds + 49152, bS, 64);
    VMC(4);
    GBAR();

    for (int tt = 0; tt < nk; ++tt) {
        const char* cb = lds + (tt & 1) * 65536;
        char* nb = lds + ((tt & 1) ^ 1) * 65536;
        const long nko = (long)((tt + 1 < nk) ? tt + 1 : nk - 1) * 128;

        auto RDA = [&](int kk, int m) {
            int lr = wm * 128 + m * 16 + l15;
            return *(const bf16x8*)(cb + kk * 32768 + lr * 64 + ((((lr >> 1) + l4) & 3) << 4));
        };
        auto RDB = [&](int kk, int n) {
            int lr = wn * 64 + n * 16 + l15;
            return *(const bf16x8*)(cb + 16384 + kk * 32768 + lr * 64 + ((((lr >> 1) + l4) & 3) << 4));
        };

        bf16x8 a[4], b0[4], b1[4];

#pragma unroll
        for (int m = 0; m < 4; ++m) a[m] = RDA(0, m);
#pragma unroll
        for (int n = 0; n < 4; ++n) b0[n] = RDB(0, n);
        STAGE(nb + 0, aS, nko);
        GBAR();
        LGKM0();
        __builtin_amdgcn_s_setprio(1);
#pragma unroll
        for (int m = 0; m < 4; ++m)
#pragma unroll
            for (int n = 0; n < 4; ++n) acc[m][n] = MFMA(a[m], b0[n], acc[m][n]);
        __builtin_amdgcn_s_setprio(0);
        GBAR();

#pragma unroll
        for (int m = 0; m < 4; ++m) a[m] = RDA(0, 4 + m);
        STAGE(nb + 16384, bS, nko);
        GBAR();
        LGKM0();
        __builtin_amdgcn_s_setprio(1);
#pragma unroll
        for (int m = 0; m < 4; ++m)
#pragma unroll
            for (int n = 0; n < 4; ++n) acc[4 + m][n] = MFMA(a[m], b0[n], acc[4 + m][n]);
        __builtin_amdgcn_s_setprio(0);
        VMC(4);
        GBAR();

#pragma unroll
        for (int m = 0; m < 4; ++m) a[m] = RDA(1, m);
#pragma unroll
        for (int n = 0; n < 4; ++n) b1[n] = RDB(1, n);
        STAGE(nb + 32768, aS, nko + 64);
        GBAR();
        LGKM0();
        __builtin_amdgcn_s_setprio(1);
#pragma unroll
        for (int m = 0; m < 4; ++m)
#pragma unroll
            for (int n = 0; n < 4; ++n) acc[m][n] = MFMA(a[m], b1[n], acc[m][n]);
        __builtin_amdgcn_s_setprio(0);
        GBAR();

#pragma unroll
        for (int m = 0; m < 4; ++m) a[m] = RDA(1, 4 + m);
        STAGE(nb + 49152, bS, nko + 64);
        GBAR();
        LGKM0();
        __builtin_amdgcn_s_setprio(1);
#pragma unroll
        for (int m = 0; m < 4; ++m)
#pragma unroll
            for (int n = 0; n < 4; ++n) acc[4 + m][n] = MFMA(a[m], b1[n], acc[4 + m][n]);
        __builtin_amdgcn_s_setprio(0);
        VMC(4);
        GBAR();
    }
    VMC(0);

    const int rq = l4 * 4;
    bf16* C = ((bf16*)Cout) + (long)z * sC;
#pragma unroll
    for (int m = 0; m < 8; ++m)
#pragma unroll
        for (int i = 0; i < 4; ++i) {
            long gr = row0 + wm * 128 + m * 16 + rq + i;
#pragma unroll
            for (int n = 0; n < 4; ++n) {
                int gc = col0 + wn * 64 + n * 16 + l15;
                C[gr * ldc + gc] = (bf16)(acc[m][n][i] * scale);
            }
        }
}

// ---------------- fp8 GEMM (round-15 best config): C = A (MxK_sub) * B^T, z = ks*zmod + mat
// 512 thr = 8 waves (2M x 4N), BM=BN=256, wave tile 128x64, K-64 slots.
// LDS 64KB: 2 slots x {A-k0 8K, A-k1 8K, B-k0 8K, B-k1 8K}; unit = 256 rows x 32B.
// 16B-half rotation u' = (u + (r>>2)) & 1 -> <=2-way bank aliasing (free) on
// ds_read_b64 fragments; gload_lds dest linear, source inverse-rotated.
// Per slot: STAGE slot s+1 first (full-slot runway >= HBM latency), 24 b64
// fragment reads + 64 MFMA (compiler-interleaved), vmcnt(0)+barrier.
// MODE 0: bf16 C = acc*scale ; MODE 1: fp8 C = acc*scale
template <int MODE>
__global__ __launch_bounds__(512, 2)
void gemmf8(const unsigned char* A, const unsigned char* Bw, void* __restrict__ Cout,
            int lda, int ldb, int ldc, int K, float scale,
            long sA, long sB, long sC, int zmod) {
    __shared__ __attribute__((aligned(16))) char lds[65536];

    const int gx = gridDim.x;
    const int nblk = gx * gridDim.y;
    const int bid = blockIdx.y * gx + blockIdx.x;
    const int cpx = nblk >> 3;
    const int sbid = (nblk & 7) ? bid : (bid & 7) * cpx + (bid >> 3);
    const int bx = sbid % gx, by = sbid / gx;

    const int z = blockIdx.z;
    const int mat = z % zmod, ks = z / zmod;
    const unsigned char* Ab = A + (long)mat * sA + (long)ks * K;
    const unsigned char* Bb = Bw + (long)mat * sB + (long)ks * K;

    const int t = threadIdx.x;
    const int lane = t & 63;
    const int w = t >> 6;
    const int wm = w >> 2;      // 0..1
    const int wn = w & 3;       // 0..3
    const int l15 = lane & 15;
    const int l4 = lane >> 4;

    const int row0 = by * 256;
    const int col0 = bx * 256;

    // staging: thread t covers unit pos t*16: row r = t>>1, stored-half t&1,
    // global-half u = ((t&1) + (r>>2)) & 1 = ((t&1) + (t>>3)) & 1
    const int r_st = t >> 1;
    const int u_g = ((t & 1) + (t >> 3)) & 1;
    const unsigned char* aSrc = Ab + (long)(row0 + r_st) * lda + u_g * 16;
    const unsigned char* bSrc = Bb + (long)(col0 + r_st) * ldb + u_g * 16;
    const int ld16 = t * 16;

    auto STAGE = [&](int slot, long koff) {
        char* base = lds + slot * 32768;
        gload_lds16(aSrc + koff,      base + ld16);            // A-k0
        gload_lds16(aSrc + koff + 32, base + 8192 + ld16);     // A-k1
        gload_lds16(bSrc + koff,      base + 16384 + ld16);    // B-k0
        gload_lds16(bSrc + koff + 32, base + 24576 + ld16);    // B-k1
    };

    floatx4 acc[8][4] = {};
    const int nk = K / 64;

    STAGE(0, 0);
    VMC(0);
    GBAR();

    for (int s = 0; s < nk; ++s) {
        const char* sb = lds + (s & 1) * 32768;
        const long pko = (long)((s + 1 < nk) ? s + 1 : nk - 1) * 64;
        STAGE((s + 1) & 1, pko);

        auto RD = [&](const char* unit, int r) {
            int addr = r * 32 + ((((l4 >> 1) + (r >> 2)) & 1) << 4) + ((l4 & 1) << 3);
            return *(const long*)(unit + addr);
        };

        long a[8], b[4];
        // kk = 0
#pragma unroll
        for (int n = 0; n < 4; ++n) b[n] = RD(sb + 16384, wn * 64 + n * 16 + l15);
#pragma unroll
        for (int m = 0; m < 8; ++m) a[m] = RD(sb, wm * 128 + m * 16 + l15);
        __builtin_amdgcn_s_setprio(1);
#pragma unroll
        for (int m = 0; m < 8; ++m)
#pragma unroll
            for (int n = 0; n < 4; ++n) acc[m][n] = MFMA8(a[m], b[n], acc[m][n]);
        __builtin_amdgcn_s_setprio(0);
        // kk = 1
#pragma unroll
        for (int n = 0; n < 4; ++n) b[n] = RD(sb + 24576, wn * 64 + n * 16 + l15);
#pragma unroll
        for (int m = 0; m < 8; ++m) a[m] = RD(sb + 8192, wm * 128 + m * 16 + l15);
        __builtin_amdgcn_s_setprio(1);
#pragma unroll
        for (int m = 0; m < 8; ++m)
#pragma unroll
            for (int n = 0; n < 4; ++n) acc[m][n] = MFMA8(a[m], b[n], acc[m][n]);
        __builtin_amdgcn_s_setprio(0);

        VMC(0);
        GBAR();
    }

    const int rq = l4 * 4;
    if constexpr (MODE == 0) {
        bf16* C = ((bf16*)Cout) + (long)z * sC;
#pragma unroll
        for (int m = 0; m < 8; ++m)
#pragma unroll
            for (int i = 0; i < 4; ++i) {
                long gr = row0 + wm * 128 + m * 16 + rq + i;
#pragma unroll
                for (int n = 0; n < 4; ++n) {
                    int gc = col0 + wn * 64 + n * 16 + l15;
                    C[gr * ldc + gc] = (bf16)(acc[m][n][i] * scale);
                }
            }
    } else {
        unsigned char* C = ((unsigned char*)Cout) + (long)z * sC;
#pragma unroll
        for (int m = 0; m < 8; ++m)
#pragma unroll
            for (int i = 0; i < 4; ++i) {
                long gr = row0 + wm * 128 + m * 16 + rq + i;
#pragma unroll
                for (int n = 0; n < 4; ++n) {
                    int gc = col0 + wn * 64 + n * 16 + l15;
                    C[gr * ldc + gc] = to_fp8(acc[m][n][i] * scale);
                }
            }
    }
}

// ---------------- reduce Gt/Wc bf16 partials (planes z=ks*2+mat, ks 0..3) -> wgc fp8 (x64) ----
__global__ void reduce_wgc(const bf16* __restrict__ p, unsigned char* __restrict__ out) {
    int i = blockIdx.x * blockDim.x + threadIdx.x;
    int e = i * 4;
    int mat = e >> 20;
    int local = e & (WW - 1);
    float s0 = 0, s1 = 0, s2 = 0, s3 = 0;
#pragma unroll
    for (int ksp = 0; ksp < 4; ++ksp) {
        bf16x4 a = *(const bf16x4*)(p + (long)(ksp * 2 + mat) * WW + local);
        s0 += (float)a[0]; s1 += (float)a[1]; s2 += (float)a[2]; s3 += (float)a[3];
    }
    unsigned int pk = to_fp8x2(s0 * 64.f, s1 * 64.f) | (to_fp8x2(s2 * 64.f, s3 * 64.f) << 16);
    *(unsigned int*)&out[e] = pk;
}

// ---------------- row softmax: bf16 scores -> fp8 probs x256 ----------------
__global__ void softmax_rows(const bf16* __restrict__ S, unsigned char* __restrict__ P,
                             const int* __restrict__ mask) {
    const int b = blockIdx.y;
    const int row = blockIdx.x;
    const bf16* srow = S + ((long)b * SEQ + row) * SEQ;
    unsigned char* prow = P + ((long)b * SEQ + row) * SEQ;
    const int* mrow = mask + b * SEQ;
    const int t = threadIdx.x;

    bf16x8 sv = *(const bf16x8*)&srow[t * 8];
    int4 m0 = ((const int4*)mrow)[t * 2];
    int4 m1 = ((const int4*)mrow)[t * 2 + 1];
    int mk[8] = {m0.x, m0.y, m0.z, m0.w, m1.x, m1.y, m1.z, m1.w};

    float v[8];
    float mx = -1e30f;
#pragma unroll
    for (int j = 0; j < 8; ++j) {
        float s = (float)sv[j];
        if (mk[j] == 0) s = -1e9f;
        v[j] = s;
        mx = fmaxf(mx, s);
    }
    __shared__ float redm[4], reds[4];
#pragma unroll
    for (int off = 32; off > 0; off >>= 1) mx = fmaxf(mx, __shfl_down(mx, off));
    if ((t & 63) == 0) redm[t >> 6] = mx;
    __syncthreads();
    mx = fmaxf(fmaxf(redm[0], redm[1]), fmaxf(redm[2], redm[3]));

    float sum = 0.f;
#pragma unroll
    for (int j = 0; j < 8; ++j) {
        v[j] = __expf(v[j] - mx);
        sum += v[j];
    }
#pragma unroll
    for (int off = 32; off > 0; off >>= 1) sum += __shfl_down(sum, off);
    if ((t & 63) == 0) reds[t >> 6] = sum;
    __syncthreads();
    sum = reds[0] + reds[1] + reds[2] + reds[3];
    float inv = 256.0f / sum;

    unsigned int lo = to_fp8x2(v[0] * inv, v[1] * inv) | (to_fp8x2(v[2] * inv, v[3] * inv) << 16);
    unsigned int hi = to_fp8x2(v[4] * inv, v[5] * inv) | (to_fp8x2(v[6] * inv, v[7] * inv) << 16);
    *(uint2*)&prow[t * 8] = make_uint2(lo, hi);
}

// ---------------- transpose VWc fp8 (yv cols 1024..2047) -> vt (1024 x SEQ per batch) ----
__global__ void transpose_v8(const unsigned char* __restrict__ yv, unsigned char* __restrict__ out) {
    __shared__ unsigned char tile[64][68];
    const int z = blockIdx.z;
    const unsigned char* ib = yv + (long)z * SEQ * 2048 + 1024;
    unsigned char* ob = out + (long)z * (long)HIDDEN * SEQ;
    const int d0 = blockIdx.x * 64;
    const int s0 = blockIdx.y * 64;
    const int t = threadIdx.x;
    const int r = t >> 4;
    const int c = (t & 15) * 4;
#pragma unroll
    for (int i = 0; i < 4; ++i) {
        uchar4 v = *(const uchar4*)&ib[(long)(s0 + r + i * 16) * 2048 + d0 + c];
        *(uchar4*)&tile[r + i * 16][c] = v;
    }
    __syncthreads();
#pragma unroll
    for (int i = 0; i < 4; ++i) {
        const int dr = r + i * 16;
        uchar4 o;
        o.x = tile[c + 0][dr]; o.y = tile[c + 1][dr];
        o.z = tile[c + 2][dr]; o.w = tile[c + 3][dr];
        *(uchar4*)&ob[(long)(d0 + dr) * SEQ + s0 + c] = o;
    }
}

// ---------------- LayerNorm fused with PV split-K reduce + bias + residual ----------------
__global__ void layernorm_out(const bf16* __restrict__ pp, const float* __restrict__ x,
                              const float* __restrict__ bo, const float* __restrict__ gamma,
                              const float* __restrict__ beta, float* __restrict__ out) {
    const long row = blockIdx.x;
    const int b = (int)(row >> 11);
    const int s = (int)(row & 2047);
    const bf16* r0 = pp + ((long)b * SEQ + s) * HIDDEN;
    const bf16* r1 = r0 + 4L * SEQ * HIDDEN;
    const int t = threadIdx.x;

    bf16x4 a0 = ((const bf16x4*)r0)[t];
    bf16x4 a1 = ((const bf16x4*)r1)[t];
    float4 xv = ((const float4*)(x + row * HIDDEN))[t];
    float4 bv = ((const float4*)bo)[t];
    float4 v;
    v.x = (float)a0[0] + (float)a1[0] + bv.x + xv.x;
    v.y = (float)a0[1] + (float)a1[1] + bv.y + xv.y;
    v.z = (float)a0[2] + (float)a1[2] + bv.z + xv.z;
    v.w = (float)a0[3] + (float)a1[3] + bv.w + xv.w;

    float ssum = v.x + v.y + v.z + v.w;
    float sq = v.x * v.x + v.y * v.y + v.z * v.z + v.w * v.w;
    __shared__ float rs[4], rq[4];
#pragma unroll
    for (int off = 32; off > 0; off >>= 1) {
        ssum += __shfl_down(ssum, off);
        sq += __shfl_down(sq, off);
    }
    if ((t & 63) == 0) { rs[t >> 6] = ssum; rq[t >> 6] = sq; }
    __syncthreads();
    ssum = rs[0] + rs[1] + rs[2] + rs[3];
    sq = rq[0] + rq[1] + rq[2] + rq[3];
    float mu = ssum * (1.0f / HIDDEN);
    float var = sq * (1.0f / HIDDEN) - mu * mu;
    float rinv = rsqrtf(var + LN_EPS);
    float4 g = ((const float4*)gamma)[t];
    float4 bt = ((const float4*)beta)[t];
    float4 o;
    o.x = (v.x - mu) * rinv * g.x + bt.x;
    o.y = (v.y - mu) * rinv * g.y + bt.y;
    o.z = (v.z - mu) * rinv * g.z + bt.z;
    o.w = (v.w - mu) * rinv * g.w + bt.w;
    ((float4*)(out + row * HIDDEN))[t] = o;
}

// ---------------- launch ----------------
extern "C" void kernel_launch(void* const* d_in, const int* in_sizes, int n_in,
                              void* d_out, int out_size, void* d_ws, size_t ws_size,
                              hipStream_t stream) {
    const float* x     = (const float*)d_in[0];
    const int*   mask  = (const int*)d_in[1];
    const float* Wq    = (const float*)d_in[2];
    const float* Wk    = (const float*)d_in[3];
    const float* Wv    = (const float*)d_in[4];
    const float* Wo    = (const float*)d_in[5];
    const float* bo    = (const float*)d_in[6];
    const float* gamma = (const float*)d_in[7];
    const float* beta  = (const float*)d_in[8];
    float* out = (float*)d_out;

    char* ws = (char*)d_ws;
    const long MB = 1024L * 1024L;
    unsigned char* xb8  = (unsigned char*)(ws + 0 * MB);   // 8 MB (8192x1024 fp8)
    unsigned char* yv8  = (unsigned char*)(ws + 8 * MB);   // 16 MB (8192x2048 fp8) [y | VWc]
    unsigned char* vt8  = (unsigned char*)(ws + 24 * MB);  // 8 MB (per batch 1024x2048 fp8)
    unsigned char* wgc8 = (unsigned char*)(ws + 32 * MB);  // 2 MB (2048x1024 fp8, x64)
    bf16* wkT = (bf16*)(ws + 34 * MB);                     // 2 MB
    bf16* wo  = (bf16*)(ws + 36 * MB);                     // 2 MB
    bf16* wqT = (bf16*)(ws + 38 * MB);                     // 2 MB
    bf16* wvT = (bf16*)(ws + 40 * MB);                     // 2 MB
    bf16* S   = (bf16*)(ws + 42 * MB);                     // 32 MB bf16 scores
    bf16* wgcp = (bf16*)(ws + 42 * MB);                    // 16 MB bf16 partials (dead before S)
    bf16* pp  = (bf16*)(ws + 42 * MB);                     // 32 MB PV partials (over S, after softmax)
    unsigned char* P8 = (unsigned char*)(ws + 74 * MB);    // 16 MB fp8 probs x256

    const int BS = BATCH * SEQ;  // 8192
    dim3 blk256(256), blk512(512);

    // input + weight prep
    cvt_f32_fp8<<<dim3(BS * HIDDEN / 8 / 256), blk256, 0, stream>>>(x, xb8, BS * HIDDEN / 8);
    transpose_w4<<<dim3(16, 16, 4), blk256, 0, stream>>>(Wq, Wk, Wv, Wo, wqT, wkT, wvT, wo);

    // Gt/Wc split-K=4 (bf16): z = ks*2 + mat, K_sub=256, bf16 partials. grid (4,4,8)
    gemm8p<0><<<dim3(1024 / 256, 1024 / 256, 8), blk512, 0, stream>>>(
        wkT, wqT, wgcp, HIDDEN, HIDDEN, HIDDEN, 256, 1.0f,
        (long)WW, (long)WW, (long)WW, 2);
    reduce_wgc<<<dim3(2 * WW / 4 / 256), blk256, 0, stream>>>(wgcp, wgc8);

    // fused projection (fp8): yv8 = xb8 * wgc8^T / 64. grid 8x32 = 256
    gemmf8<1><<<dim3(2048 / 256, BS / 256, 1), blk512, 0, stream>>>(
        xb8, wgc8, yv8, HIDDEN, HIDDEN, 2048, HIDDEN, 1.0f / 64.0f, 0, 0, 0, 1);

    // VWc -> vt per batch (fp8)
    transpose_v8<<<dim3(HIDDEN / 64, SEQ / 64, BATCH), blk256, 0, stream>>>(yv8, vt8);

    // scores (fp8 in, bf16 out): per batch y * x^T * SCALE. grid 8x8x4 = 256
    gemmf8<0><<<dim3(SEQ / 256, SEQ / 256, BATCH), blk512, 0, stream>>>(
        yv8, xb8, S, 2048, HIDDEN, SEQ, HIDDEN, ATT_SCALE,
        (long)SEQ * 2048, (long)SEQ * HIDDEN, (long)SEQ * SEQ, 4);

    // softmax -> fp8 probs x256
    softmax_rows<<<dim3(SEQ, BATCH), blk256, 0, stream>>>(S, P8, mask);

    // PV split-K=2 (fp8): z = ks*4 + b, K_sub=1024, bf16 partials x(1/256). grid (4,8,8)
    gemmf8<0><<<dim3(HIDDEN / 256, SEQ / 256, 8), blk512, 0, stream>>>(
        P8, vt8, pp, SEQ, SEQ, HIDDEN, 1024, 1.0f / 256.0f,
        (long)SEQ * SEQ, (long)HIDDEN * SEQ, (long)SEQ * HIDDEN, 4);

    // LN fused with partial-reduce + bias + residual
    layernorm_out<<<dim3(BS), blk256, 0, stream>>>(pp, x, bo, gamma, beta, out);
}

// Round 18
// 154.317 us; speedup vs baseline: 1.2208x; 1.0648x over previous
//
#include <hip/hip_runtime.h>

typedef __bf16 bf16;
typedef __bf16 bf16x8 __attribute__((ext_vector_type(8)));
typedef __bf16 bf16x4 __attribute__((ext_vector_type(4)));
typedef float floatx4 __attribute__((ext_vector_type(4)));

#define HIDDEN 1024
#define SEQ 2048
#define BATCH 4
#define ATT_SCALE 0.0625f
#define LN_EPS 1e-5f
#define WW (HIDDEN * HIDDEN)

__device__ __forceinline__ void gload_lds16(const void* g, void* l) {
    __builtin_amdgcn_global_load_lds(
        (const __attribute__((address_space(1))) unsigned int*)g,
        (__attribute__((address_space(3))) unsigned int*)l, 16, 0, 0);
}

#define GBAR() asm volatile("s_barrier" ::: "memory")
#define LGKM0() asm volatile("s_waitcnt lgkmcnt(0)" ::: "memory")
#define VMC(N) asm volatile("s_waitcnt vmcnt(" #N ")" ::: "memory")
#define MFMA(a, b, c) __builtin_amdgcn_mfma_f32_16x16x32_bf16(a, b, c, 0, 0, 0)
#define MFMA8(a, b, c) __builtin_amdgcn_mfma_f32_16x16x32_fp8_fp8(a, b, c, 0, 0, 0)

// fp8 e4m3 conversions via hardware cvt_pk (saturating)
__device__ __forceinline__ unsigned char to_fp8(float f) {
    return (unsigned char)(__builtin_amdgcn_cvt_pk_fp8_f32(f, 0.0f, 0, 0) & 0xff);
}
__device__ __forceinline__ unsigned int to_fp8x2(float a, float b) {
    return __builtin_amdgcn_cvt_pk_fp8_f32(a, b, 0, 0) & 0xffff;
}

// ---------------- fp32 -> fp8 conversion (8 elems/thread) ----------------
__global__ void cvt_f32_fp8(const float* __restrict__ in, unsigned char* __restrict__ out, int n8) {
    int i = blockIdx.x * blockDim.x + threadIdx.x;
    if (i >= n8) return;
    float4 v0 = ((const float4*)in)[i * 2];
    float4 v1 = ((const float4*)in)[i * 2 + 1];
    unsigned int lo = to_fp8x2(v0.x, v0.y) | (to_fp8x2(v0.z, v0.w) << 16);
    unsigned int hi = to_fp8x2(v1.x, v1.y) | (to_fp8x2(v1.z, v1.w) << 16);
    ((uint2*)out)[i] = make_uint2(lo, hi);
}

// ---------------- weight prep: z=0..2 transpose fp32->bf16 ; z=3 plain convert Wo ----------
__global__ void transpose_w4(const float* __restrict__ s0, const float* __restrict__ s1,
                             const float* __restrict__ s2, const float* __restrict__ s3,
                             bf16* __restrict__ d0p, bf16* __restrict__ d1p,
                             bf16* __restrict__ d2p, bf16* __restrict__ d3p) {
    const int zz = blockIdx.z;
    const float* in = (zz == 0) ? s0 : (zz == 1) ? s1 : (zz == 2) ? s2 : s3;
    bf16* out = (zz == 0) ? d0p : (zz == 1) ? d1p : (zz == 2) ? d2p : d3p;
    const int d0 = blockIdx.x * 64;
    const int f0 = blockIdx.y * 64;
    const int t = threadIdx.x;
    const int r = t >> 4;
    const int c = (t & 15) * 4;
    if (zz == 3) {
#pragma unroll
        for (int i = 0; i < 4; ++i) {
            float4 v = *(const float4*)&in[(long)(f0 + r + i * 16) * HIDDEN + d0 + c];
            bf16x4 b;
            b[0] = (bf16)v.x; b[1] = (bf16)v.y; b[2] = (bf16)v.z; b[3] = (bf16)v.w;
            *(bf16x4*)&out[(long)(f0 + r + i * 16) * HIDDEN + d0 + c] = b;
        }
        return;
    }
    __shared__ __attribute__((aligned(16))) bf16 tile[64][72];
#pragma unroll
    for (int i = 0; i < 4; ++i) {
        float4 v = *(const float4*)&in[(long)(f0 + r + i * 16) * HIDDEN + d0 + c];
        bf16x4 b;
        b[0] = (bf16)v.x; b[1] = (bf16)v.y; b[2] = (bf16)v.z; b[3] = (bf16)v.w;
        *(bf16x4*)&tile[r + i * 16][c] = b;
    }
    __syncthreads();
#pragma unroll
    for (int i = 0; i < 4; ++i) {
        const int dr = r + i * 16;
        bf16x4 o;
#pragma unroll
        for (int j = 0; j < 4; ++j) o[j] = tile[c + j][dr];
        *(bf16x4*)&out[(long)(d0 + dr) * HIDDEN + f0 + c] = o;
    }
}

// ---------------- bf16 8-phase GEMM (weight prep only): C = A*B^T, z = ks*zmod + mat ----
template <int MODE>
__global__ __launch_bounds__(512, 2)
void gemm8p(const bf16* A, const bf16* Bw, void* __restrict__ Cout,
            int lda, int ldb, int ldc, int K, float scale,
            long sA, long sB, long sC, int zmod) {
    __shared__ __attribute__((aligned(16))) char lds[131072];

    const int gx = gridDim.x;
    const int nblk = gx * gridDim.y;
    const int bid = blockIdx.y * gx + blockIdx.x;
    const int cpx = nblk >> 3;
    const int sbid = (nblk & 7) ? bid : (bid & 7) * cpx + (bid >> 3);
    const int bx = sbid % gx, by = sbid / gx;

    const int z = blockIdx.z;
    const int mat = z % zmod, ks = z / zmod;
    const char* Ab = (const char*)(A + (long)mat * sA + (long)ks * K);
    const char* Bb = (const char*)(Bw + (long)mat * sB + (long)ks * K);
    const long lda2 = lda * 2L, ldb2 = ldb * 2L;

    const int t = threadIdx.x;
    const int lane = t & 63;
    const int w = t >> 6;
    const int wm = w >> 2;
    const int wn = w & 3;
    const int l15 = lane & 15;
    const int l4 = lane >> 4;

    const int row0 = by * 256;
    const int col0 = bx * 256;

    const int sc = ((((t & 3) - ((t >> 3) & 3)) & 3) << 4);
    const char* aS[2];
    const char* bS[2];
#pragma unroll
    for (int uu = 0; uu < 2; ++uu) {
        aS[uu] = Ab + (long)(row0 + uu * 128 + (t >> 2)) * lda2 + sc;
        bS[uu] = Bb + (long)(col0 + uu * 128 + (t >> 2)) * ldb2 + sc;
    }

    auto STAGE = [&](char* dstu, const char* const* sp, long koff) {
        gload_lds16(sp[0] + koff, dstu + t * 16);
        gload_lds16(sp[1] + koff, dstu + 8192 + t * 16);
    };

    floatx4 acc[8][4] = {};
    const int nk = K / 64;

    STAGE(lds + 0,     aS, 0);
    STAGE(lds + 16384, bS, 0);
    STAGE(lds + 32768, aS, 64);
    STAGE(lds + 49152, bS, 64);
    VMC(4);
    GBAR();

    for (int tt = 0; tt < nk; ++tt) {
        const char* cb = lds + (tt & 1) * 65536;
        char* nb = lds + ((tt & 1) ^ 1) * 65536;
        const long nko = (long)((tt + 1 < nk) ? tt + 1 : nk - 1) * 128;

        auto RDA = [&](int kk, int m) {
            int lr = wm * 128 + m * 16 + l15;
            return *(const bf16x8*)(cb + kk * 32768 + lr * 64 + ((((lr >> 1) + l4) & 3) << 4));
        };
        auto RDB = [&](int kk, int n) {
            int lr = wn * 64 + n * 16 + l15;
            return *(const bf16x8*)(cb + 16384 + kk * 32768 + lr * 64 + ((((lr >> 1) + l4) & 3) << 4));
        };

        bf16x8 a[4], b0[4], b1[4];

#pragma unroll
        for (int m = 0; m < 4; ++m) a[m] = RDA(0, m);
#pragma unroll
        for (int n = 0; n < 4; ++n) b0[n] = RDB(0, n);
        STAGE(nb + 0, aS, nko);
        GBAR();
        LGKM0();
        __builtin_amdgcn_s_setprio(1);
#pragma unroll
        for (int m = 0; m < 4; ++m)
#pragma unroll
            for (int n = 0; n < 4; ++n) acc[m][n] = MFMA(a[m], b0[n], acc[m][n]);
        __builtin_amdgcn_s_setprio(0);
        GBAR();

#pragma unroll
        for (int m = 0; m < 4; ++m) a[m] = RDA(0, 4 + m);
        STAGE(nb + 16384, bS, nko);
        GBAR();
        LGKM0();
        __builtin_amdgcn_s_setprio(1);
#pragma unroll
        for (int m = 0; m < 4; ++m)
#pragma unroll
            for (int n = 0; n < 4; ++n) acc[4 + m][n] = MFMA(a[m], b0[n], acc[4 + m][n]);
        __builtin_amdgcn_s_setprio(0);
        VMC(4);
        GBAR();

#pragma unroll
        for (int m = 0; m < 4; ++m) a[m] = RDA(1, m);
#pragma unroll
        for (int n = 0; n < 4; ++n) b1[n] = RDB(1, n);
        STAGE(nb + 32768, aS, nko + 64);
        GBAR();
        LGKM0();
        __builtin_amdgcn_s_setprio(1);
#pragma unroll
        for (int m = 0; m < 4; ++m)
#pragma unroll
            for (int n = 0; n < 4; ++n) acc[m][n] = MFMA(a[m], b1[n], acc[m][n]);
        __builtin_amdgcn_s_setprio(0);
        GBAR();

#pragma unroll
        for (int m = 0; m < 4; ++m) a[m] = RDA(1, 4 + m);
        STAGE(nb + 49152, bS, nko + 64);
        GBAR();
        LGKM0();
        __builtin_amdgcn_s_setprio(1);
#pragma unroll
        for (int m = 0; m < 4; ++m)
#pragma unroll
            for (int n = 0; n < 4; ++n) acc[4 + m][n] = MFMA(a[m], b1[n], acc[4 + m][n]);
        __builtin_amdgcn_s_setprio(0);
        VMC(4);
        GBAR();
    }
    VMC(0);

    const int rq = l4 * 4;
    bf16* C = ((bf16*)Cout) + (long)z * sC;
#pragma unroll
    for (int m = 0; m < 8; ++m)
#pragma unroll
        for (int i = 0; i < 4; ++i) {
            long gr = row0 + wm * 128 + m * 16 + rq + i;
#pragma unroll
            for (int n = 0; n < 4; ++n) {
                int gc = col0 + wn * 64 + n * 16 + l15;
                C[gr * ldc + gc] = (bf16)(acc[m][n][i] * scale);
            }
        }
}

// ---------------- fp8 GEMM, BM=128 x BN=256, 8 waves, 2 blocks/CU: z = ks*zmod + mat ---
// 512 thr = 8 waves (2M x 4N), wave tile 64x64, K-64 slots. LDS 48KB: 2 slots x
// {A-k0 4K, A-k1 4K, B-k0 8K, B-k1 8K}; A unit = 128 rows x 32B, B unit = 256 rows
// x 32B. 16B-half rotation u' = (u + (r>>2)) & 1 (<=2-way = free); gload_lds dest
// linear, source inverse-rotated. Per slot: STAGE s+1 first (3 gloads/thread), 16
// b64 frag reads + 32 MFMA per wave (compiler-interleaved), vmcnt(0)+barrier.
// 48KB LDS + ~100 VGPR -> 2 co-resident 8-wave blocks per CU (grids = 512) hide
// each other's drain (the r12-r16 missing cell: big blocks AND co-residency).
// MODE 0: bf16 C = acc*scale ; MODE 1: fp8 C = acc*scale
template <int MODE>
__global__ __launch_bounds__(512, 4)
void gemmf8(const unsigned char* A, const unsigned char* Bw, void* __restrict__ Cout,
            int lda, int ldb, int ldc, int K, float scale,
            long sA, long sB, long sC, int zmod) {
    __shared__ __attribute__((aligned(16))) char lds[49152];

    const int gx = gridDim.x;
    const int nblk = gx * gridDim.y;
    const int bid = blockIdx.y * gx + blockIdx.x;
    const int cpx = nblk >> 3;
    const int sbid = (nblk & 7) ? bid : (bid & 7) * cpx + (bid >> 3);
    const int bx = sbid % gx, by = sbid / gx;

    const int z = blockIdx.z;
    const int mat = z % zmod, ks = z / zmod;
    const unsigned char* Ab = A + (long)mat * sA + (long)ks * K;
    const unsigned char* Bb = Bw + (long)mat * sB + (long)ks * K;

    const int t = threadIdx.x;
    const int lane = t & 63;
    const int w = t >> 6;
    const int wm = w >> 2;      // 0..1 -> rows wm*64
    const int wn = w & 3;       // 0..3 -> cols wn*64
    const int l15 = lane & 15;
    const int l4 = lane >> 4;

    const int row0 = by * 128;
    const int col0 = bx * 256;

    // staging sources (inverse half-rotation):
    // g0 (A, 8KB covers k0|k1): r = (t&255)>>1, kk = t>>8, half h = t&1,
    //    global half u = (h + (r>>2)) & 1
    const int rA = (t & 255) >> 1;
    const int uA = ((t & 1) + (rA >> 2)) & 1;
    const unsigned char* aSrc = Ab + (long)(row0 + rA) * lda + (t >> 8) * 32 + uA * 16;
    // g1/g2 (B, 8KB each): r = t>>1, u = ((t&1) + (t>>3)) & 1
    const int uB = ((t & 1) + (t >> 3)) & 1;
    const unsigned char* bSrc = Bb + (long)(col0 + (t >> 1)) * ldb + uB * 16;
    const int ld16 = t * 16;

    auto STAGE = [&](int slot, long koff) {
        char* base = lds + slot * 24576;
        gload_lds16(aSrc + koff,      base + ld16);            // A k0|k1 (by thread)
        gload_lds16(bSrc + koff,      base + 8192 + ld16);     // B-k0
        gload_lds16(bSrc + koff + 32, base + 16384 + ld16);    // B-k1
    };

    floatx4 acc[4][4] = {};
    const int nk = K / 64;

    STAGE(0, 0);
    VMC(0);
    GBAR();

    for (int s = 0; s < nk; ++s) {
        const char* sb = lds + (s & 1) * 24576;
        const long pko = (long)((s + 1 < nk) ? s + 1 : nk - 1) * 64;
        STAGE((s + 1) & 1, pko);

        auto RD = [&](const char* unit, int r) {
            int addr = r * 32 + ((((l4 >> 1) + (r >> 2)) & 1) << 4) + ((l4 & 1) << 3);
            return *(const long*)(unit + addr);
        };

        long a[4], b[4];
        // kk = 0: A unit at 0 (128 rows), B unit at 8192 (256 rows)
#pragma unroll
        for (int n = 0; n < 4; ++n) b[n] = RD(sb + 8192, wn * 64 + n * 16 + l15);
#pragma unroll
        for (int m = 0; m < 4; ++m) a[m] = RD(sb, wm * 64 + m * 16 + l15);
        __builtin_amdgcn_s_setprio(1);
#pragma unroll
        for (int m = 0; m < 4; ++m)
#pragma unroll
            for (int n = 0; n < 4; ++n) acc[m][n] = MFMA8(a[m], b[n], acc[m][n]);
        __builtin_amdgcn_s_setprio(0);
        // kk = 1: A unit at 4096, B unit at 16384
#pragma unroll
        for (int n = 0; n < 4; ++n) b[n] = RD(sb + 16384, wn * 64 + n * 16 + l15);
#pragma unroll
        for (int m = 0; m < 4; ++m) a[m] = RD(sb + 4096, wm * 64 + m * 16 + l15);
        __builtin_amdgcn_s_setprio(1);
#pragma unroll
        for (int m = 0; m < 4; ++m)
#pragma unroll
            for (int n = 0; n < 4; ++n) acc[m][n] = MFMA8(a[m], b[n], acc[m][n]);
        __builtin_amdgcn_s_setprio(0);

        VMC(0);
        GBAR();
    }

    const int rq = l4 * 4;
    if constexpr (MODE == 0) {
        bf16* C = ((bf16*)Cout) + (long)z * sC;
#pragma unroll
        for (int m = 0; m < 4; ++m)
#pragma unroll
            for (int i = 0; i < 4; ++i) {
                long gr = row0 + wm * 64 + m * 16 + rq + i;
#pragma unroll
                for (int n = 0; n < 4; ++n) {
                    int gc = col0 + wn * 64 + n * 16 + l15;
                    C[gr * ldc + gc] = (bf16)(acc[m][n][i] * scale);
                }
            }
    } else {
        unsigned char* C = ((unsigned char*)Cout) + (long)z * sC;
#pragma unroll
        for (int m = 0; m < 4; ++m)
#pragma unroll
            for (int i = 0; i < 4; ++i) {
                long gr = row0 + wm * 64 + m * 16 + rq + i;
#pragma unroll
                for (int n = 0; n < 4; ++n) {
                    int gc = col0 + wn * 64 + n * 16 + l15;
                    C[gr * ldc + gc] = to_fp8(acc[m][n][i] * scale);
                }
            }
    }
}

// ---------------- reduce Gt/Wc bf16 partials (planes z=ks*2+mat, ks 0..3) -> wgc fp8 (x64) ----
__global__ void reduce_wgc(const bf16* __restrict__ p, unsigned char* __restrict__ out) {
    int i = blockIdx.x * blockDim.x + threadIdx.x;
    int e = i * 4;
    int mat = e >> 20;
    int local = e & (WW - 1);
    float s0 = 0, s1 = 0, s2 = 0, s3 = 0;
#pragma unroll
    for (int ksp = 0; ksp < 4; ++ksp) {
        bf16x4 a = *(const bf16x4*)(p + (long)(ksp * 2 + mat) * WW + local);
        s0 += (float)a[0]; s1 += (float)a[1]; s2 += (float)a[2]; s3 += (float)a[3];
    }
    unsigned int pk = to_fp8x2(s0 * 64.f, s1 * 64.f) | (to_fp8x2(s2 * 64.f, s3 * 64.f) << 16);
    *(unsigned int*)&out[e] = pk;
}

// ---------------- row softmax: bf16 scores -> fp8 probs x256 ----------------
__global__ void softmax_rows(const bf16* __restrict__ S, unsigned char* __restrict__ P,
                             const int* __restrict__ mask) {
    const int b = blockIdx.y;
    const int row = blockIdx.x;
    const bf16* srow = S + ((long)b * SEQ + row) * SEQ;
    unsigned char* prow = P + ((long)b * SEQ + row) * SEQ;
    const int* mrow = mask + b * SEQ;
    const int t = threadIdx.x;

    bf16x8 sv = *(const bf16x8*)&srow[t * 8];
    int4 m0 = ((const int4*)mrow)[t * 2];
    int4 m1 = ((const int4*)mrow)[t * 2 + 1];
    int mk[8] = {m0.x, m0.y, m0.z, m0.w, m1.x, m1.y, m1.z, m1.w};

    float v[8];
    float mx = -1e30f;
#pragma unroll
    for (int j = 0; j < 8; ++j) {
        float s = (float)sv[j];
        if (mk[j] == 0) s = -1e9f;
        v[j] = s;
        mx = fmaxf(mx, s);
    }
    __shared__ float redm[4], reds[4];
#pragma unroll
    for (int off = 32; off > 0; off >>= 1) mx = fmaxf(mx, __shfl_down(mx, off));
    if ((t & 63) == 0) redm[t >> 6] = mx;
    __syncthreads();
    mx = fmaxf(fmaxf(redm[0], redm[1]), fmaxf(redm[2], redm[3]));

    float sum = 0.f;
#pragma unroll
    for (int j = 0; j < 8; ++j) {
        v[j] = __expf(v[j] - mx);
        sum += v[j];
    }
#pragma unroll
    for (int off = 32; off > 0; off >>= 1) sum += __shfl_down(sum, off);
    if ((t & 63) == 0) reds[t >> 6] = sum;
    __syncthreads();
    sum = reds[0] + reds[1] + reds[2] + reds[3];
    float inv = 256.0f / sum;

    unsigned int lo = to_fp8x2(v[0] * inv, v[1] * inv) | (to_fp8x2(v[2] * inv, v[3] * inv) << 16);
    unsigned int hi = to_fp8x2(v[4] * inv, v[5] * inv) | (to_fp8x2(v[6] * inv, v[7] * inv) << 16);
    *(uint2*)&prow[t * 8] = make_uint2(lo, hi);
}

// ---------------- transpose VWc fp8 (yv cols 1024..2047) -> vt (1024 x SEQ per batch) ----
__global__ void transpose_v8(const unsigned char* __restrict__ yv, unsigned char* __restrict__ out) {
    __shared__ unsigned char tile[64][68];
    const int z = blockIdx.z;
    const unsigned char* ib = yv + (long)z * SEQ * 2048 + 1024;
    unsigned char* ob = out + (long)z * (long)HIDDEN * SEQ;
    const int d0 = blockIdx.x * 64;
    const int s0 = blockIdx.y * 64;
    const int t = threadIdx.x;
    const int r = t >> 4;
    const int c = (t & 15) * 4;
#pragma unroll
    for (int i = 0; i < 4; ++i) {
        uchar4 v = *(const uchar4*)&ib[(long)(s0 + r + i * 16) * 2048 + d0 + c];
        *(uchar4*)&tile[r + i * 16][c] = v;
    }
    __syncthreads();
#pragma unroll
    for (int i = 0; i < 4; ++i) {
        const int dr = r + i * 16;
        uchar4 o;
        o.x = tile[c + 0][dr]; o.y = tile[c + 1][dr];
        o.z = tile[c + 2][dr]; o.w = tile[c + 3][dr];
        *(uchar4*)&ob[(long)(d0 + dr) * SEQ + s0 + c] = o;
    }
}

// ---------------- LayerNorm fused with PV split-K reduce + bias + residual ----------------
__global__ void layernorm_out(const bf16* __restrict__ pp, const float* __restrict__ x,
                              const float* __restrict__ bo, const float* __restrict__ gamma,
                              const float* __restrict__ beta, float* __restrict__ out) {
    const long row = blockIdx.x;
    const int b = (int)(row >> 11);
    const int s = (int)(row & 2047);
    const bf16* r0 = pp + ((long)b * SEQ + s) * HIDDEN;
    const bf16* r1 = r0 + 4L * SEQ * HIDDEN;
    const int t = threadIdx.x;

    bf16x4 a0 = ((const bf16x4*)r0)[t];
    bf16x4 a1 = ((const bf16x4*)r1)[t];
    float4 xv = ((const float4*)(x + row * HIDDEN))[t];
    float4 bv = ((const float4*)bo)[t];
    float4 v;
    v.x = (float)a0[0] + (float)a1[0] + bv.x + xv.x;
    v.y = (float)a0[1] + (float)a1[1] + bv.y + xv.y;
    v.z = (float)a0[2] + (float)a1[2] + bv.z + xv.z;
    v.w = (float)a0[3] + (float)a1[3] + bv.w + xv.w;

    float ssum = v.x + v.y + v.z + v.w;
    float sq = v.x * v.x + v.y * v.y + v.z * v.z + v.w * v.w;
    __shared__ float rs[4], rq[4];
#pragma unroll
    for (int off = 32; off > 0; off >>= 1) {
        ssum += __shfl_down(ssum, off);
        sq += __shfl_down(sq, off);
    }
    if ((t & 63) == 0) { rs[t >> 6] = ssum; rq[t >> 6] = sq; }
    __syncthreads();
    ssum = rs[0] + rs[1] + rs[2] + rs[3];
    sq = rq[0] + rq[1] + rq[2] + rq[3];
    float mu = ssum * (1.0f / HIDDEN);
    float var = sq * (1.0f / HIDDEN) - mu * mu;
    float rinv = rsqrtf(var + LN_EPS);
    float4 g = ((const float4*)gamma)[t];
    float4 bt = ((const float4*)beta)[t];
    float4 o;
    o.x = (v.x - mu) * rinv * g.x + bt.x;
    o.y = (v.y - mu) * rinv * g.y + bt.y;
    o.z = (v.z - mu) * rinv * g.z + bt.z;
    o.w = (v.w - mu) * rinv * g.w + bt.w;
    ((float4*)(out + row * HIDDEN))[t] = o;
}

// ---------------- launch ----------------
extern "C" void kernel_launch(void* const* d_in, const int* in_sizes, int n_in,
                              void* d_out, int out_size, void* d_ws, size_t ws_size,
                              hipStream_t stream) {
    const float* x     = (const float*)d_in[0];
    const int*   mask  = (const int*)d_in[1];
    const float* Wq    = (const float*)d_in[2];
    const float* Wk    = (const float*)d_in[3];
    const float* Wv    = (const float*)d_in[4];
    const float* Wo    = (const float*)d_in[5];
    const float* bo    = (const float*)d_in[6];
    const float* gamma = (const float*)d_in[7];
    const float* beta  = (const float*)d_in[8];
    float* out = (float*)d_out;

    char* ws = (char*)d_ws;
    const long MB = 1024L * 1024L;
    unsigned char* xb8  = (unsigned char*)(ws + 0 * MB);   // 8 MB (8192x1024 fp8)
    unsigned char* yv8  = (unsigned char*)(ws + 8 * MB);   // 16 MB (8192x2048 fp8) [y | VWc]
    unsigned char* vt8  = (unsigned char*)(ws + 24 * MB);  // 8 MB (per batch 1024x2048 fp8)
    unsigned char* wgc8 = (unsigned char*)(ws + 32 * MB);  // 2 MB (2048x1024 fp8, x64)
    bf16* wkT = (bf16*)(ws + 34 * MB);                     // 2 MB
    bf16* wo  = (bf16*)(ws + 36 * MB);                     // 2 MB
    bf16* wqT = (bf16*)(ws + 38 * MB);                     // 2 MB
    bf16* wvT = (bf16*)(ws + 40 * MB);                     // 2 MB
    bf16* S   = (bf16*)(ws + 42 * MB);                     // 32 MB bf16 scores
    bf16* wgcp = (bf16*)(ws + 42 * MB);                    // 16 MB bf16 partials (dead before S)
    bf16* pp  = (bf16*)(ws + 42 * MB);                     // 32 MB PV partials (over S, after softmax)
    unsigned char* P8 = (unsigned char*)(ws + 74 * MB);    // 16 MB fp8 probs x256

    const int BS = BATCH * SEQ;  // 8192
    dim3 blk256(256), blk512(512);

    // input + weight prep
    cvt_f32_fp8<<<dim3(BS * HIDDEN / 8 / 256), blk256, 0, stream>>>(x, xb8, BS * HIDDEN / 8);
    transpose_w4<<<dim3(16, 16, 4), blk256, 0, stream>>>(Wq, Wk, Wv, Wo, wqT, wkT, wvT, wo);

    // Gt/Wc split-K=4 (bf16): z = ks*2 + mat, K_sub=256, bf16 partials. grid (4,4,8)
    gemm8p<0><<<dim3(1024 / 256, 1024 / 256, 8), blk512, 0, stream>>>(
        wkT, wqT, wgcp, HIDDEN, HIDDEN, HIDDEN, 256, 1.0f,
        (long)WW, (long)WW, (long)WW, 2);
    reduce_wgc<<<dim3(2 * WW / 4 / 256), blk256, 0, stream>>>(wgcp, wgc8);

    // fused projection (fp8): yv8 = xb8 * wgc8^T / 64. grid (8,64) = 512 -> 2 blocks/CU
    gemmf8<1><<<dim3(2048 / 256, BS / 128, 1), blk512, 0, stream>>>(
        xb8, wgc8, yv8, HIDDEN, HIDDEN, 2048, HIDDEN, 1.0f / 64.0f, 0, 0, 0, 1);

    // VWc -> vt per batch (fp8)
    transpose_v8<<<dim3(HIDDEN / 64, SEQ / 64, BATCH), blk256, 0, stream>>>(yv8, vt8);

    // scores (fp8 in, bf16 out): per batch y * x^T * SCALE. grid (8,16,4) = 512
    gemmf8<0><<<dim3(SEQ / 256, SEQ / 128, BATCH), blk512, 0, stream>>>(
        yv8, xb8, S, 2048, HIDDEN, SEQ, HIDDEN, ATT_SCALE,
        (long)SEQ * 2048, (long)SEQ * HIDDEN, (long)SEQ * SEQ, 4);

    // softmax -> fp8 probs x256
    softmax_rows<<<dim3(SEQ, BATCH), blk256, 0, stream>>>(S, P8, mask);

    // PV split-K=2 (fp8): z = ks*4 + b, K_sub=1024, bf16 partials x(1/256). grid (4,16,8) = 512
    gemmf8<0><<<dim3(HIDDEN / 256, SEQ / 128, 8), blk512, 0, stream>>>(
        P8, vt8, pp, SEQ, SEQ, HIDDEN, 1024, 1.0f / 256.0f,
        (long)SEQ * SEQ, (long)HIDDEN * SEQ, (long)SEQ * HIDDEN, 4);

    // LN fused with partial-reduce + bias + residual
    layernorm_out<<<dim3(BS), blk256, 0, stream>>>(pp, x, bo, gamma, beta, out);
}